// Round 7
// baseline (11580.823 us; speedup 1.0000x reference)
//
#include <hip/hip_runtime.h>
#include <math.h>

#define TT 200
#define BB 16384
#define HH 20

// f64 weight store (element offsets)
#define OWIH0 0        // 160   W_ih0 [80,2]
#define OWHH0 160      // 1600  W_hh0 [80,20]
#define OB0   1760     // 80    b_ih0 + b_hh0
#define OWIH1 1840     // 1600  W_ih1 [80,20]
#define OWHH1 3440     // 1600  W_hh1 [80,20]
#define OB1   5040     // 80    b_ih1 + b_hh1
#define OWDEC 5120     // 12000 W_dec [3,4000]
#define OBDEC 17120    // 3     b_dec
#define WTOT  17123

__device__ double g_wd[WTOT];

// ---------- JAX threefry2x32, key = jax.random.key(42) = [0, 42] ----------
__device__ __forceinline__ void tf2x32(unsigned x0, unsigned x1,
                                       unsigned* o0, unsigned* o1) {
  const unsigned ks0 = 0u, ks1 = 42u;
  const unsigned ks2 = ks0 ^ ks1 ^ 0x1BD11BDAu;
  x0 += ks0; x1 += ks1;
#define ROTL_(v, d) (((v) << (d)) | ((v) >> (32 - (d))))
#define RND_(r) { x0 += x1; x1 = ROTL_(x1, r); x1 ^= x0; }
  RND_(13) RND_(15) RND_(26) RND_(6)
  x0 += ks1; x1 += ks2 + 1u;
  RND_(17) RND_(29) RND_(16) RND_(24)
  x0 += ks2; x1 += ks0 + 2u;
  RND_(13) RND_(15) RND_(26) RND_(6)
  x0 += ks0; x1 += ks1 + 3u;
  RND_(17) RND_(29) RND_(16) RND_(24)
  x0 += ks1; x1 += ks2 + 4u;
  RND_(13) RND_(15) RND_(26) RND_(6)
  x0 += ks2; x1 += ks0 + 5u;
  *o0 = x0; *o1 = x1;
#undef RND_
#undef ROTL_
}

// uniform bits -> gumbel sample (f32 bit manipulation exact; logs in f64)
__device__ __forceinline__ double bits2gumbel(unsigned bits) {
  float f = __uint_as_float((bits >> 9) | 0x3F800000u) - 1.0f;
  float uf = (f > 0.0f) ? f : 1.17549435e-38f;  // max(tiny, f) semantics
  return -log(-log((double)uf));
}

// ---------- fast f64 exp, |x| <= 70 ----------
__device__ __forceinline__ double fexp64(double x) {
  const double LOG2E = 1.4426950408889634;
  const double SHIFT = 6755399441055744.0;  // 1.5 * 2^52
  double td = fma(x, LOG2E, SHIFT);
  double kd = td - SHIFT;
  int k = __double2loint(td);
  double r = fma(-kd, 6.93147180369123816490e-01, x);
  r = fma(-kd, 1.90821492927058770002e-10, r);
  double p = 2.505210838544172e-08;
  p = fma(p, r, 2.755731922398589e-07);
  p = fma(p, r, 2.755731922398589e-06);
  p = fma(p, r, 2.48015873015873e-05);
  p = fma(p, r, 1.984126984126984e-04);
  p = fma(p, r, 1.388888888888889e-03);
  p = fma(p, r, 8.333333333333333e-03);
  p = fma(p, r, 4.1666666666666664e-02);
  p = fma(p, r, 1.6666666666666666e-01);
  p = fma(p, r, 0.5);
  p = fma(p, r, 1.0);
  p = fma(p, r, 1.0);
  double two_k = __hiloint2double((1023 + k) << 20, 0);
  return p * two_k;
}

__device__ __forceinline__ double sigm64(double v) {
  double vc = fmin(fmax(v, -70.0), 70.0);
  return 1.0 / (1.0 + fexp64(-vc));
}
__device__ __forceinline__ double tanh64(double v) {
  double vc = fmin(fmax(2.0 * v, -70.0), 70.0);
  return 1.0 - 2.0 / (1.0 + fexp64(vc));
}

__global__ void prep_kernel(
    const float* __restrict__ W_ih0, const float* __restrict__ W_hh0,
    const float* __restrict__ b_ih0, const float* __restrict__ b_hh0,
    const float* __restrict__ W_ih1, const float* __restrict__ W_hh1,
    const float* __restrict__ b_ih1, const float* __restrict__ b_hh1,
    const float* __restrict__ W_dec, const float* __restrict__ b_dec) {
  int i = blockIdx.x * blockDim.x + threadIdx.x;
  if (i < 160) g_wd[i] = (double)W_ih0[i];
  else if (i < 1760) g_wd[i] = (double)W_hh0[i - 160];
  else if (i < 1840) { int r = i - 1760; g_wd[i] = (double)b_ih0[r] + (double)b_hh0[r]; }
  else if (i < 3440) g_wd[i] = (double)W_ih1[i - 1840];
  else if (i < 5040) g_wd[i] = (double)W_hh1[i - 3440];
  else if (i < 5120) { int r = i - 5040; g_wd[i] = (double)b_ih1[r] + (double)b_hh1[r]; }
  else if (i < 17120) g_wd[i] = (double)W_dec[i - 5120];
  else if (i < WTOT) g_wd[i] = (double)b_dec[i - 17120];
}

// One thread = one batch element, end to end. f32 in/out, f64 compute.
__global__ __launch_bounds__(64, 1) void lstm_thread_kernel(
    const float* __restrict__ x,      // [T,B,2]
    const float* __restrict__ h0_in,  // [2,B,20]
    const float* __restrict__ c0_in,  // [2,B,20]
    float* __restrict__ out) {
  const int b = blockIdx.x * 64 + (int)threadIdx.x;

  double h0[HH], c0[HH], h1[HH], c1[HH];
#pragma unroll
  for (int j = 0; j < HH; ++j) {
    h0[j] = (double)h0_in[0 * BB * HH + b * HH + j];
    c0[j] = (double)c0_in[0 * BB * HH + b * HH + j];
    h1[j] = (double)h0_in[1 * BB * HH + b * HH + j];
    c1[j] = (double)c0_in[1 * BB * HH + b * HH + j];
  }

  double lg0 = 0.0, lg1 = 0.0, lg2 = 0.0;
  const float2* x2 = (const float2*)x;

  for (int t = 0; t < TT; ++t) {
    float2 xv = x2[t * BB + b];
    double x0 = (double)xv.x, x1 = (double)xv.y;

    double h0n[HH], h1n[HH];

    // ---- layer 0 (rows: i=u, f=20+u, g=40+u, o=60+u)
#pragma unroll
    for (int u = 0; u < HH; ++u) {
      double ai = g_wd[OB0 + u];
      double af = g_wd[OB0 + 20 + u];
      double ag = g_wd[OB0 + 40 + u];
      double ao = g_wd[OB0 + 60 + u];
      ai = fma(g_wd[OWIH0 + (u)*2 + 0], x0, ai);
      ai = fma(g_wd[OWIH0 + (u)*2 + 1], x1, ai);
      af = fma(g_wd[OWIH0 + (20 + u) * 2 + 0], x0, af);
      af = fma(g_wd[OWIH0 + (20 + u) * 2 + 1], x1, af);
      ag = fma(g_wd[OWIH0 + (40 + u) * 2 + 0], x0, ag);
      ag = fma(g_wd[OWIH0 + (40 + u) * 2 + 1], x1, ag);
      ao = fma(g_wd[OWIH0 + (60 + u) * 2 + 0], x0, ao);
      ao = fma(g_wd[OWIH0 + (60 + u) * 2 + 1], x1, ao);
#pragma unroll
      for (int j = 0; j < HH; ++j) {
        double hj = h0[j];
        ai = fma(g_wd[OWHH0 + (u)*HH + j], hj, ai);
        af = fma(g_wd[OWHH0 + (20 + u) * HH + j], hj, af);
        ag = fma(g_wd[OWHH0 + (40 + u) * HH + j], hj, ag);
        ao = fma(g_wd[OWHH0 + (60 + u) * HH + j], hj, ao);
      }
      double si = sigm64(ai), sf = sigm64(af);
      double tg = tanh64(ag), so = sigm64(ao);
      double c = fma(sf, c0[u], si * tg);
      c0[u] = c;
      h0n[u] = so * tanh64(c);
    }

    // ---- layer 1: input h0n (same timestep), recurrent h1
#pragma unroll
    for (int u = 0; u < HH; ++u) {
      double ai = g_wd[OB1 + u];
      double af = g_wd[OB1 + 20 + u];
      double ag = g_wd[OB1 + 40 + u];
      double ao = g_wd[OB1 + 60 + u];
#pragma unroll
      for (int j = 0; j < HH; ++j) {
        double hj = h0n[j];
        ai = fma(g_wd[OWIH1 + (u)*HH + j], hj, ai);
        af = fma(g_wd[OWIH1 + (20 + u) * HH + j], hj, af);
        ag = fma(g_wd[OWIH1 + (40 + u) * HH + j], hj, ag);
        ao = fma(g_wd[OWIH1 + (60 + u) * HH + j], hj, ao);
      }
#pragma unroll
      for (int j = 0; j < HH; ++j) {
        double hj = h1[j];
        ai = fma(g_wd[OWHH1 + (u)*HH + j], hj, ai);
        af = fma(g_wd[OWHH1 + (20 + u) * HH + j], hj, af);
        ag = fma(g_wd[OWHH1 + (40 + u) * HH + j], hj, ag);
        ao = fma(g_wd[OWHH1 + (60 + u) * HH + j], hj, ao);
      }
      double si = sigm64(ai), sf = sigm64(af);
      double tg = tanh64(ag), so = sigm64(ao);
      double c = fma(sf, c1[u], si * tg);
      c1[u] = c;
      h1n[u] = so * tanh64(c);
    }

    // ---- decoder accumulation + state commit
#pragma unroll
    for (int u = 0; u < HH; ++u) {
      double h = h1n[u];
      int col = t * HH + u;
      lg0 = fma(g_wd[OWDEC + col], h, lg0);
      lg1 = fma(g_wd[OWDEC + 4000 + col], h, lg1);
      lg2 = fma(g_wd[OWDEC + 8000 + col], h, lg2);
      h0[u] = h0n[u];
      h1[u] = h1n[u];
    }
  }

  // ---- outputs: action[B], logp[B], h_n[2,B,20], c_n[2,B,20]
#pragma unroll
  for (int j = 0; j < HH; ++j) {
    out[2 * BB + 0 * BB * HH + b * HH + j] = (float)h0[j];
    out[2 * BB + 1 * BB * HH + b * HH + j] = (float)h1[j];
    out[2 * BB + 2 * BB * HH + 0 * BB * HH + b * HH + j] = (float)c0[j];
    out[2 * BB + 2 * BB * HH + 1 * BB * HH + b * HH + j] = (float)c1[j];
  }

  double l[3];
  l[0] = g_wd[OBDEC + 0] + lg0;
  l[1] = g_wd[OBDEC + 1] + lg1;
  l[2] = g_wd[OBDEC + 2] + lg2;

  // ---- sampling: PRIMARY = partitionable 32-bit stream = hi ^ lo output
  // words of threefry2x32(key, (counter_hi=0, counter_lo=flat_idx)).
  // Alternates for diagnostics: legacy iota-split; hi word alone; lo word.
  int act_p = 0, act_x0 = 0, act_x1 = 0, act_old = 0;
  double bp = -1e300, b0 = -1e300, b1v = -1e300, bo = -1e300;
#pragma unroll
  for (int a = 0; a < 3; ++a) {
    unsigned idx = 3u * (unsigned)b + (unsigned)a;  // flat (b,a) of (16384,3)

    unsigned p0, p1;
    tf2x32(0u, idx, &p0, &p1);               // partitionable counter (0, i)
    double g_x = bits2gumbel(p0 ^ p1);       // PRIMARY: xor of both words
    double g_0 = bits2gumbel(p0);
    double g_1 = bits2gumbel(p1);

    unsigned q = (idx < 24576u) ? idx : (idx - 24576u);
    unsigned o0, o1;
    tf2x32(q, 24576u + q, &o0, &o1);         // legacy split-half
    double g_o = bits2gumbel((idx < 24576u) ? o0 : o1);

    double v;
    v = l[a] + g_x; if (v > bp) { bp = v; act_p = a; }
    v = l[a] + g_0; if (v > b0) { b0 = v; act_x0 = a; }
    v = l[a] + g_1; if (v > b1v) { b1v = v; act_x1 = a; }
    v = l[a] + g_o; if (v > bo) { bo = v; act_old = a; }
  }

  double m = fmax(l[0], fmax(l[1], l[2]));
  double se = exp(l[0] - m) + exp(l[1] - m) + exp(l[2] - m);
  double lp = (l[act_p] - m) - log(se);

  // diagnostic encoding: fractional offsets flag which alternates disagree
  float diag = 0.0f;
  if (act_old != act_p) diag += 0.016f;
  if (act_x0 != act_p) diag += 0.008f;
  if (act_x1 != act_p) diag += 0.004f;

  out[b] = (float)act_p + diag;
  out[BB + b] = (float)lp;
}

extern "C" void kernel_launch(void* const* d_in, const int* in_sizes, int n_in,
                              void* d_out, int out_size, void* d_ws, size_t ws_size,
                              hipStream_t stream) {
  prep_kernel<<<dim3((WTOT + 255) / 256), dim3(256), 0, stream>>>(
      (const float*)d_in[3], (const float*)d_in[4],
      (const float*)d_in[5], (const float*)d_in[6],
      (const float*)d_in[7], (const float*)d_in[8],
      (const float*)d_in[9], (const float*)d_in[10],
      (const float*)d_in[11], (const float*)d_in[12]);
  lstm_thread_kernel<<<dim3(BB / 64), dim3(64), 0, stream>>>(
      (const float*)d_in[0], (const float*)d_in[1], (const float*)d_in[2],
      (float*)d_out);
}

// Round 8
// 9808.265 us; speedup vs baseline: 1.1807x; 1.1807x over previous
//
#include <hip/hip_runtime.h>
#include <math.h>

#define TT 200
#define BB 16384
#define HH 20

// f64 weight store (element offsets)
#define OWIH0 0        // 160   W_ih0 [80,2]
#define OWHH0 160      // 1600  W_hh0 [80,20]
#define OB0   1760     // 80    b_ih0 + b_hh0
#define OWIH1 1840     // 1600  W_ih1 [80,20]
#define OWHH1 3440     // 1600  W_hh1 [80,20]
#define OB1   5040     // 80    b_ih1 + b_hh1
#define OWDEC 5120     // 12000 W_dec [3,4000]
#define OBDEC 17120    // 3     b_dec
#define WTOT  17123

__device__ double g_wd[WTOT];

// ---------- JAX threefry2x32, key = jax.random.key(42) = [0, 42] ----------
__device__ __forceinline__ void tf2x32(unsigned x0, unsigned x1,
                                       unsigned* o0, unsigned* o1) {
  const unsigned ks0 = 0u, ks1 = 42u;
  const unsigned ks2 = ks0 ^ ks1 ^ 0x1BD11BDAu;
  x0 += ks0; x1 += ks1;
#define ROTL_(v, d) (((v) << (d)) | ((v) >> (32 - (d))))
#define RND_(r) { x0 += x1; x1 = ROTL_(x1, r); x1 ^= x0; }
  RND_(13) RND_(15) RND_(26) RND_(6)
  x0 += ks1; x1 += ks2 + 1u;
  RND_(17) RND_(29) RND_(16) RND_(24)
  x0 += ks2; x1 += ks0 + 2u;
  RND_(13) RND_(15) RND_(26) RND_(6)
  x0 += ks0; x1 += ks1 + 3u;
  RND_(17) RND_(29) RND_(16) RND_(24)
  x0 += ks1; x1 += ks2 + 4u;
  RND_(13) RND_(15) RND_(26) RND_(6)
  x0 += ks2; x1 += ks0 + 5u;
  *o0 = x0; *o1 = x1;
#undef RND_
#undef ROTL_
}

// uniform bits -> gumbel sample (f32 bit manipulation exact; logs in f64)
__device__ __forceinline__ double bits2gumbel(unsigned bits) {
  float f = __uint_as_float((bits >> 9) | 0x3F800000u) - 1.0f;
  float uf = (f > 0.0f) ? f : 1.17549435e-38f;  // max(tiny, f) semantics
  return -log(-log((double)uf));
}

// ---------- fast f64 exp, |x| <= 70 ----------
__device__ __forceinline__ double fexp64(double x) {
  const double LOG2E = 1.4426950408889634;
  const double SHIFT = 6755399441055744.0;  // 1.5 * 2^52
  double td = fma(x, LOG2E, SHIFT);
  double kd = td - SHIFT;
  int k = __double2loint(td);
  double r = fma(-kd, 6.93147180369123816490e-01, x);
  r = fma(-kd, 1.90821492927058770002e-10, r);
  double p = 2.505210838544172e-08;
  p = fma(p, r, 2.755731922398589e-07);
  p = fma(p, r, 2.755731922398589e-06);
  p = fma(p, r, 2.48015873015873e-05);
  p = fma(p, r, 1.984126984126984e-04);
  p = fma(p, r, 1.388888888888889e-03);
  p = fma(p, r, 8.333333333333333e-03);
  p = fma(p, r, 4.1666666666666664e-02);
  p = fma(p, r, 1.6666666666666666e-01);
  p = fma(p, r, 0.5);
  p = fma(p, r, 1.0);
  p = fma(p, r, 1.0);
  double two_k = __hiloint2double((1023 + k) << 20, 0);
  return p * two_k;
}

__device__ __forceinline__ double sigm64(double v) {
  double vc = fmin(fmax(v, -70.0), 70.0);
  return 1.0 / (1.0 + fexp64(-vc));
}
__device__ __forceinline__ double tanh64(double v) {
  double vc = fmin(fmax(2.0 * v, -70.0), 70.0);
  return 1.0 - 2.0 / (1.0 + fexp64(vc));
}

__global__ void prep_kernel(
    const float* __restrict__ W_ih0, const float* __restrict__ W_hh0,
    const float* __restrict__ b_ih0, const float* __restrict__ b_hh0,
    const float* __restrict__ W_ih1, const float* __restrict__ W_hh1,
    const float* __restrict__ b_ih1, const float* __restrict__ b_hh1,
    const float* __restrict__ W_dec, const float* __restrict__ b_dec) {
  int i = blockIdx.x * blockDim.x + threadIdx.x;
  if (i < 160) g_wd[i] = (double)W_ih0[i];
  else if (i < 1760) g_wd[i] = (double)W_hh0[i - 160];
  else if (i < 1840) { int r = i - 1760; g_wd[i] = (double)b_ih0[r] + (double)b_hh0[r]; }
  else if (i < 3440) g_wd[i] = (double)W_ih1[i - 1840];
  else if (i < 5040) g_wd[i] = (double)W_hh1[i - 3440];
  else if (i < 5120) { int r = i - 5040; g_wd[i] = (double)b_ih1[r] + (double)b_hh1[r]; }
  else if (i < 17120) g_wd[i] = (double)W_dec[i - 5120];
  else if (i < WTOT) g_wd[i] = (double)b_dec[i - 17120];
}

// layer-0: NU units starting at unit row0; inputs x0,x1 and hp[20]
template <int NU>
__device__ __forceinline__ void l0_units(int row0, double x0, double x1,
                                         const double* hp,
                                         double* c_st, double* h_new) {
  double acc[NU][4];
#pragma unroll
  for (int u = 0; u < NU; ++u) {
#pragma unroll
    for (int g = 0; g < 4; ++g) {
      int row = g * 20 + row0 + u;
      double a = g_wd[OB0 + row];
      a = fma(g_wd[OWIH0 + row * 2 + 0], x0, a);
      a = fma(g_wd[OWIH0 + row * 2 + 1], x1, a);
      acc[u][g] = a;
    }
  }
#pragma unroll
  for (int j = 0; j < HH; ++j) {
    double hj = hp[j];
#pragma unroll
    for (int u = 0; u < NU; ++u)
#pragma unroll
      for (int g = 0; g < 4; ++g)
        acc[u][g] = fma(g_wd[OWHH0 + (g * 20 + row0 + u) * HH + j], hj, acc[u][g]);
  }
#pragma unroll
  for (int u = 0; u < NU; ++u) {
    double si = sigm64(acc[u][0]), sf = sigm64(acc[u][1]);
    double tg = tanh64(acc[u][2]), so = sigm64(acc[u][3]);
    double c = fma(sf, c_st[u], si * tg);
    c_st[u] = c;
    h_new[u] = so * tanh64(c);
  }
}

// layer-1: 4 units starting at row0; inputs hp0 (layer-0 h) and hp1 (own h)
__device__ __forceinline__ void l1_units(int row0, const double* hp0,
                                         const double* hp1,
                                         double* c_st, double* h_new) {
  double acc[4][4];
#pragma unroll
  for (int u = 0; u < 4; ++u)
#pragma unroll
    for (int g = 0; g < 4; ++g)
      acc[u][g] = g_wd[OB1 + g * 20 + row0 + u];
#pragma unroll
  for (int j = 0; j < HH; ++j) {
    double hj = hp0[j];
#pragma unroll
    for (int u = 0; u < 4; ++u)
#pragma unroll
      for (int g = 0; g < 4; ++g)
        acc[u][g] = fma(g_wd[OWIH1 + (g * 20 + row0 + u) * HH + j], hj, acc[u][g]);
  }
#pragma unroll
  for (int j = 0; j < HH; ++j) {
    double hj = hp1[j];
#pragma unroll
    for (int u = 0; u < 4; ++u)
#pragma unroll
      for (int g = 0; g < 4; ++g)
        acc[u][g] = fma(g_wd[OWHH1 + (g * 20 + row0 + u) * HH + j], hj, acc[u][g]);
  }
#pragma unroll
  for (int u = 0; u < 4; ++u) {
    double si = sigm64(acc[u][0]), sf = sigm64(acc[u][1]);
    double tg = tanh64(acc[u][2]), so = sigm64(acc[u][3]);
    double c = fma(sf, c_st[u], si * tg);
    c_st[u] = c;
    h_new[u] = so * tanh64(c);
  }
}

// 8 waves / 64 elements: waves 0-2 = layer-0 units {7,7,6}; waves 3-7 =
// layer-1 units {4 each}, pipelined one timestep behind layer 0.
__global__ __launch_bounds__(512, 2) void lstm_wave_kernel(
    const float* __restrict__ x,      // [T,B,2]
    const float* __restrict__ h0_in,  // [2,B,20]
    const float* __restrict__ c0_in,  // [2,B,20]
    float* __restrict__ out) {
  __shared__ double s_h0[64][21];       // stride 21 f64 = 42 dwords, gcd(42,32)=2
  __shared__ double s_h1[64][21];
  __shared__ double s_logit[5][64][3];

  const int lane = threadIdx.x & 63;
  const int wv = threadIdx.x >> 6;        // 0..7
  const int eg = blockIdx.x * 64 + lane;

  const bool isL0 = (wv < 3);
  int u0, nu;
  if (isL0) { u0 = wv * 7; nu = (wv == 2) ? 6 : 7; }
  else      { u0 = (wv - 3) * 4; nu = 4; }

  double c_st[7], h_new[7];
  double lg0 = 0.0, lg1 = 0.0, lg2 = 0.0;

  // init state from h0/c0 inputs
  {
    const int l = isL0 ? 0 : 1;
#pragma unroll
    for (int u = 0; u < 7; ++u) {
      if (u < nu) {
        c_st[u] = (double)c0_in[l * BB * HH + eg * HH + u0 + u];
        double h = (double)h0_in[l * BB * HH + eg * HH + u0 + u];
        if (isL0) s_h0[lane][u0 + u] = h; else s_h1[lane][u0 + u] = h;
      }
      h_new[u] = 0.0;
    }
  }
  __syncthreads();

  const float2* x2 = (const float2*)x;

  // phase s: layer0 computes t=s (s<200); layer1 computes t=s-1 (s>=1)
  for (int s = 0; s <= TT; ++s) {
    if (isL0) {
      if (s < TT) {
        float2 xv = x2[s * BB + eg];
        double x0 = (double)xv.x, x1 = (double)xv.y;
        double hp[HH];
#pragma unroll
        for (int j = 0; j < HH; ++j) hp[j] = s_h0[lane][j];
        if (nu == 7) l0_units<7>(u0, x0, x1, hp, c_st, h_new);
        else         l0_units<6>(u0, x0, x1, hp, c_st, h_new);
      }
    } else {
      if (s >= 1) {
        double hp0[HH], hp1[HH];
#pragma unroll
        for (int j = 0; j < HH; ++j) hp0[j] = s_h0[lane][j];
#pragma unroll
        for (int j = 0; j < HH; ++j) hp1[j] = s_h1[lane][j];
        l1_units(u0, hp0, hp1, c_st, h_new);
        const int t1 = s - 1;
#pragma unroll
        for (int u = 0; u < 4; ++u) {
          double h = h_new[u];
          int col = t1 * HH + u0 + u;
          lg0 = fma(g_wd[OWDEC + col], h, lg0);
          lg1 = fma(g_wd[OWDEC + 4000 + col], h, lg1);
          lg2 = fma(g_wd[OWDEC + 8000 + col], h, lg2);
        }
      }
    }
    __syncthreads();
    if (isL0) {
      if (s < TT) {
#pragma unroll
        for (int u = 0; u < 7; ++u) if (u < nu) s_h0[lane][u0 + u] = h_new[u];
      }
    } else {
      if (s >= 1) {
#pragma unroll
        for (int u = 0; u < 4; ++u) s_h1[lane][u0 + u] = h_new[u];
      }
    }
    __syncthreads();
  }

  // outputs: action[B], logp[B], h_n[2,B,20], c_n[2,B,20]
  {
    const int l = isL0 ? 0 : 1;
#pragma unroll
    for (int u = 0; u < 7; ++u) {
      if (u < nu) {
        out[2 * BB + l * BB * HH + eg * HH + u0 + u] = (float)h_new[u];
        out[2 * BB + 2 * BB * HH + l * BB * HH + eg * HH + u0 + u] = (float)c_st[u];
      }
    }
  }

  if (!isL0) {
    s_logit[wv - 3][lane][0] = lg0;
    s_logit[wv - 3][lane][1] = lg1;
    s_logit[wv - 3][lane][2] = lg2;
  }
  __syncthreads();

  if (wv == 0) {
    double l[3];
#pragma unroll
    for (int a = 0; a < 3; ++a) {
      double v = g_wd[OBDEC + a];
#pragma unroll
      for (int k = 0; k < 5; ++k) v += s_logit[k][lane][a];
      l[a] = v;
    }

    // partitionable 32-bit stream: hi^lo of threefry2x32(key, (0, flat_idx))
    int act = 0;
    double vbest = -1.0e300;
#pragma unroll
    for (int a = 0; a < 3; ++a) {
      unsigned idx = 3u * (unsigned)eg + (unsigned)a;
      unsigned p0, p1;
      tf2x32(0u, idx, &p0, &p1);
      double g = bits2gumbel(p0 ^ p1);
      double v = l[a] + g;
      if (v > vbest) { vbest = v; act = a; }  // strict >: first max (argmax)
    }
    double m = fmax(l[0], fmax(l[1], l[2]));
    double se = exp(l[0] - m) + exp(l[1] - m) + exp(l[2] - m);
    double lp = (l[act] - m) - log(se);
    out[eg] = (float)act;
    out[BB + eg] = (float)lp;
  }
}

extern "C" void kernel_launch(void* const* d_in, const int* in_sizes, int n_in,
                              void* d_out, int out_size, void* d_ws, size_t ws_size,
                              hipStream_t stream) {
  prep_kernel<<<dim3((WTOT + 255) / 256), dim3(256), 0, stream>>>(
      (const float*)d_in[3], (const float*)d_in[4],
      (const float*)d_in[5], (const float*)d_in[6],
      (const float*)d_in[7], (const float*)d_in[8],
      (const float*)d_in[9], (const float*)d_in[10],
      (const float*)d_in[11], (const float*)d_in[12]);
  lstm_wave_kernel<<<dim3(BB / 64), dim3(512), 0, stream>>>(
      (const float*)d_in[0], (const float*)d_in[1], (const float*)d_in[2],
      (float*)d_out);
}

// Round 9
// 3355.655 us; speedup vs baseline: 3.4511x; 2.9229x over previous
//
#include <hip/hip_runtime.h>
#include <math.h>

#define TT 200
#define BB 16384
#define HH 20

// f64 weight store (element offsets)
#define OWIH0 0        // 160   W_ih0 [80,2]
#define OWHH0 160      // 1600  W_hh0 [80,20]
#define OB0   1760     // 80    b_ih0 + b_hh0
#define OWIH1 1840     // 1600  W_ih1 [80,20]
#define OWHH1 3440     // 1600  W_hh1 [80,20]
#define OB1   5040     // 80    b_ih1 + b_hh1
#define OWDEC 5120     // 12000 W_dec [3,4000]
#define OBDEC 17120    // 3     b_dec
#define WTOT  17123

__device__ double g_wd[WTOT];

// ---------- JAX threefry2x32, key = jax.random.key(42) = [0, 42] ----------
__device__ __forceinline__ void tf2x32(unsigned x0, unsigned x1,
                                       unsigned* o0, unsigned* o1) {
  const unsigned ks0 = 0u, ks1 = 42u;
  const unsigned ks2 = ks0 ^ ks1 ^ 0x1BD11BDAu;
  x0 += ks0; x1 += ks1;
#define ROTL_(v, d) (((v) << (d)) | ((v) >> (32 - (d))))
#define RND_(r) { x0 += x1; x1 = ROTL_(x1, r); x1 ^= x0; }
  RND_(13) RND_(15) RND_(26) RND_(6)
  x0 += ks1; x1 += ks2 + 1u;
  RND_(17) RND_(29) RND_(16) RND_(24)
  x0 += ks2; x1 += ks0 + 2u;
  RND_(13) RND_(15) RND_(26) RND_(6)
  x0 += ks0; x1 += ks1 + 3u;
  RND_(17) RND_(29) RND_(16) RND_(24)
  x0 += ks1; x1 += ks2 + 4u;
  RND_(13) RND_(15) RND_(26) RND_(6)
  x0 += ks2; x1 += ks0 + 5u;
  *o0 = x0; *o1 = x1;
#undef RND_
#undef ROTL_
}

// uniform bits -> gumbel sample (f32 bit manipulation exact; logs in f64)
__device__ __forceinline__ double bits2gumbel(unsigned bits) {
  float f = __uint_as_float((bits >> 9) | 0x3F800000u) - 1.0f;
  float uf = (f > 0.0f) ? f : 1.17549435e-38f;  // max(tiny, f) semantics
  return -log(-log((double)uf));
}

// ---------- fast f64 exp, |x| <= 70 ----------
__device__ __forceinline__ double fexp64(double x) {
  const double LOG2E = 1.4426950408889634;
  const double SHIFT = 6755399441055744.0;  // 1.5 * 2^52
  double td = fma(x, LOG2E, SHIFT);
  double kd = td - SHIFT;
  int k = __double2loint(td);
  double r = fma(-kd, 6.93147180369123816490e-01, x);
  r = fma(-kd, 1.90821492927058770002e-10, r);
  double p = 2.505210838544172e-08;
  p = fma(p, r, 2.755731922398589e-07);
  p = fma(p, r, 2.755731922398589e-06);
  p = fma(p, r, 2.48015873015873e-05);
  p = fma(p, r, 1.984126984126984e-04);
  p = fma(p, r, 1.388888888888889e-03);
  p = fma(p, r, 8.333333333333333e-03);
  p = fma(p, r, 4.1666666666666664e-02);
  p = fma(p, r, 1.6666666666666666e-01);
  p = fma(p, r, 0.5);
  p = fma(p, r, 1.0);
  p = fma(p, r, 1.0);
  double two_k = __hiloint2double((1023 + k) << 20, 0);
  return p * two_k;
}

__device__ __forceinline__ double sigm64(double v) {
  double vc = fmin(fmax(v, -70.0), 70.0);
  return 1.0 / (1.0 + fexp64(-vc));
}
__device__ __forceinline__ double tanh64(double v) {
  double vc = fmin(fmax(2.0 * v, -70.0), 70.0);
  return 1.0 - 2.0 / (1.0 + fexp64(vc));
}

__global__ void prep_kernel(
    const float* __restrict__ W_ih0, const float* __restrict__ W_hh0,
    const float* __restrict__ b_ih0, const float* __restrict__ b_hh0,
    const float* __restrict__ W_ih1, const float* __restrict__ W_hh1,
    const float* __restrict__ b_ih1, const float* __restrict__ b_hh1,
    const float* __restrict__ W_dec, const float* __restrict__ b_dec) {
  int i = blockIdx.x * blockDim.x + threadIdx.x;
  if (i < 160) g_wd[i] = (double)W_ih0[i];
  else if (i < 1760) g_wd[i] = (double)W_hh0[i - 160];
  else if (i < 1840) { int r = i - 1760; g_wd[i] = (double)b_ih0[r] + (double)b_hh0[r]; }
  else if (i < 3440) g_wd[i] = (double)W_ih1[i - 1840];
  else if (i < 5040) g_wd[i] = (double)W_hh1[i - 3440];
  else if (i < 5120) { int r = i - 5040; g_wd[i] = (double)b_ih1[r] + (double)b_hh1[r]; }
  else if (i < 17120) g_wd[i] = (double)W_dec[i - 5120];
  else if (i < WTOT) g_wd[i] = (double)b_dec[i - 17120];
}

// layer-0 chunk: NC units at rows row0.. ; acc[NC][4] live, h written to LDS.
template <int NC>
__device__ __forceinline__ void l0_chunk(int row0, double x0, double x1,
                                         const double* hp, double* c_st,
                                         double* dst) {
  double acc[NC][4];
#pragma unroll
  for (int u = 0; u < NC; ++u) {
#pragma unroll
    for (int g = 0; g < 4; ++g) {
      int row = g * 20 + row0 + u;
      double a = g_wd[OB0 + row];
      a = fma(g_wd[OWIH0 + row * 2 + 0], x0, a);
      a = fma(g_wd[OWIH0 + row * 2 + 1], x1, a);
      acc[u][g] = a;
    }
  }
#pragma unroll
  for (int j = 0; j < HH; ++j) {
    double hj = hp[j];
#pragma unroll
    for (int u = 0; u < NC; ++u)
#pragma unroll
      for (int g = 0; g < 4; ++g)
        acc[u][g] = fma(g_wd[OWHH0 + (g * 20 + row0 + u) * HH + j], hj, acc[u][g]);
  }
#pragma unroll
  for (int u = 0; u < NC; ++u) {
    double si = sigm64(acc[u][0]), sf = sigm64(acc[u][1]);
    double tg = tanh64(acc[u][2]), so = sigm64(acc[u][3]);
    double c = fma(sf, c_st[u], si * tg);
    c_st[u] = c;
    dst[u] = so * tanh64(c);
  }
}

// layer-1 chunk: NC units; hp0 cached in regs, recurrent h1 streamed from LDS.
template <int NC>
__device__ __forceinline__ void l1_chunk(int row0, const double* hp0,
                                         const double* h1r, double* c_st,
                                         double* dst, int t1, double* lg) {
  double acc[NC][4];
#pragma unroll
  for (int u = 0; u < NC; ++u)
#pragma unroll
    for (int g = 0; g < 4; ++g)
      acc[u][g] = g_wd[OB1 + g * 20 + row0 + u];
#pragma unroll
  for (int j = 0; j < HH; ++j) {
    double hj = hp0[j];
#pragma unroll
    for (int u = 0; u < NC; ++u)
#pragma unroll
      for (int g = 0; g < 4; ++g)
        acc[u][g] = fma(g_wd[OWIH1 + (g * 20 + row0 + u) * HH + j], hj, acc[u][g]);
  }
#pragma unroll
  for (int j = 0; j < HH; ++j) {
    double hj = h1r[j];  // LDS stream (ds_read_b64)
#pragma unroll
    for (int u = 0; u < NC; ++u)
#pragma unroll
      for (int g = 0; g < 4; ++g)
        acc[u][g] = fma(g_wd[OWHH1 + (g * 20 + row0 + u) * HH + j], hj, acc[u][g]);
  }
#pragma unroll
  for (int u = 0; u < NC; ++u) {
    double si = sigm64(acc[u][0]), sf = sigm64(acc[u][1]);
    double tg = tanh64(acc[u][2]), so = sigm64(acc[u][3]);
    double c = fma(sf, c_st[u], si * tg);
    c_st[u] = c;
    double h = so * tanh64(c);
    dst[u] = h;
    int col = t1 * HH + row0 + u;
    lg[0] = fma(g_wd[OWDEC + col], h, lg[0]);
    lg[1] = fma(g_wd[OWDEC + 4000 + col], h, lg[1]);
    lg[2] = fma(g_wd[OWDEC + 8000 + col], h, lg[2]);
  }
}

// 8 waves / 64 elements; double-buffered h; one barrier per phase.
__global__ __launch_bounds__(512, 2) void lstm_wave_kernel(
    const float* __restrict__ x,      // [T,B,2]
    const float* __restrict__ h0_in,  // [2,B,20]
    const float* __restrict__ c0_in,  // [2,B,20]
    float* __restrict__ out) {
  __shared__ double s_h0[2][64][21];
  __shared__ double s_h1[2][64][21];
  __shared__ double s_logit[5][64][3];

  const int lane = threadIdx.x & 63;
  const int wv = __builtin_amdgcn_readfirstlane((int)(threadIdx.x >> 6));
  const int eg = blockIdx.x * 64 + lane;

  const bool isL0 = (wv < 3);
  int u0r = isL0 ? wv * 7 : (wv - 3) * 4;
  const int u0 = __builtin_amdgcn_readfirstlane(u0r);
  const int nu = isL0 ? ((wv == 2) ? 6 : 7) : 4;

  double c_st[7];
  double lg[3] = {0.0, 0.0, 0.0};

  // init: h(-1) into buffer 1 (phase 0 / phase 1 read it there)
  {
    const int l = isL0 ? 0 : 1;
#pragma unroll
    for (int u = 0; u < 7; ++u) {
      if (u < nu) {
        c_st[u] = (double)c0_in[l * BB * HH + eg * HH + u0 + u];
        double h = (double)h0_in[l * BB * HH + eg * HH + u0 + u];
        if (isL0) s_h0[1][lane][u0 + u] = h;
        else      s_h1[1][lane][u0 + u] = h;
      }
    }
  }
  __syncthreads();

  const float2* x2 = (const float2*)x;

  // phase s: L0 computes t=s (s<200), h(t) -> buffer t&1, reads (t-1)&1.
  //          L1 computes t1=s-1 (s>=1): h0(t1) from t1&1, own h1(t1-1) from
  //          (t1+1)&1, writes h1(t1) -> t1&1.
  for (int s = 0; s <= TT; ++s) {
    if (isL0) {
      if (s < TT) {
        const int rb = (s + 1) & 1;
        const int wb = s & 1;
        float2 xv = x2[s * BB + eg];
        double x0 = (double)xv.x, x1 = (double)xv.y;
        double hp[HH];
#pragma unroll
        for (int j = 0; j < HH; ++j) hp[j] = s_h0[rb][lane][j];
        double* dst = &s_h0[wb][lane][0];
        if (nu == 7) {
          l0_chunk<2>(u0 + 0, x0, x1, hp, c_st + 0, dst + u0 + 0);
          l0_chunk<2>(u0 + 2, x0, x1, hp, c_st + 2, dst + u0 + 2);
          l0_chunk<2>(u0 + 4, x0, x1, hp, c_st + 4, dst + u0 + 4);
          l0_chunk<1>(u0 + 6, x0, x1, hp, c_st + 6, dst + u0 + 6);
        } else {
          l0_chunk<2>(u0 + 0, x0, x1, hp, c_st + 0, dst + u0 + 0);
          l0_chunk<2>(u0 + 2, x0, x1, hp, c_st + 2, dst + u0 + 2);
          l0_chunk<2>(u0 + 4, x0, x1, hp, c_st + 4, dst + u0 + 4);
        }
      }
    } else {
      if (s >= 1) {
        const int t1 = s - 1;
        const int h0b = t1 & 1;
        const int h1rb = (t1 + 1) & 1;
        double hp0[HH];
#pragma unroll
        for (int j = 0; j < HH; ++j) hp0[j] = s_h0[h0b][lane][j];
        const double* h1r = &s_h1[h1rb][lane][0];
        double* dst = &s_h1[h0b][lane][0];
        l1_chunk<2>(u0 + 0, hp0, h1r, c_st + 0, dst + u0 + 0, t1, lg);
        l1_chunk<2>(u0 + 2, hp0, h1r, c_st + 2, dst + u0 + 2, t1, lg);
      }
    }
    __syncthreads();
  }

  // final states: h0(199) in s_h0[1], h1(199) in s_h1[1] (199&1 == 1)
  {
    const int l = isL0 ? 0 : 1;
#pragma unroll
    for (int u = 0; u < 7; ++u) {
      if (u < nu) {
        double hfin = isL0 ? s_h0[1][lane][u0 + u] : s_h1[1][lane][u0 + u];
        out[2 * BB + l * BB * HH + eg * HH + u0 + u] = (float)hfin;
        out[2 * BB + 2 * BB * HH + l * BB * HH + eg * HH + u0 + u] = (float)c_st[u];
      }
    }
  }

  if (!isL0) {
    s_logit[wv - 3][lane][0] = lg[0];
    s_logit[wv - 3][lane][1] = lg[1];
    s_logit[wv - 3][lane][2] = lg[2];
  }
  __syncthreads();

  if (wv == 0) {
    double l[3];
#pragma unroll
    for (int a = 0; a < 3; ++a) {
      double v = g_wd[OBDEC + a];
#pragma unroll
      for (int k = 0; k < 5; ++k) v += s_logit[k][lane][a];
      l[a] = v;
    }

    // partitionable 32-bit stream: hi^lo of threefry2x32(key, (0, flat_idx))
    int act = 0;
    double vbest = -1.0e300;
#pragma unroll
    for (int a = 0; a < 3; ++a) {
      unsigned idx = 3u * (unsigned)eg + (unsigned)a;
      unsigned p0, p1;
      tf2x32(0u, idx, &p0, &p1);
      double g = bits2gumbel(p0 ^ p1);
      double v = l[a] + g;
      if (v > vbest) { vbest = v; act = a; }  // strict >: first max (argmax)
    }
    double m = fmax(l[0], fmax(l[1], l[2]));
    double se = exp(l[0] - m) + exp(l[1] - m) + exp(l[2] - m);
    double lp = (l[act] - m) - log(se);
    out[eg] = (float)act;
    out[BB + eg] = (float)lp;
  }
}

extern "C" void kernel_launch(void* const* d_in, const int* in_sizes, int n_in,
                              void* d_out, int out_size, void* d_ws, size_t ws_size,
                              hipStream_t stream) {
  prep_kernel<<<dim3((WTOT + 255) / 256), dim3(256), 0, stream>>>(
      (const float*)d_in[3], (const float*)d_in[4],
      (const float*)d_in[5], (const float*)d_in[6],
      (const float*)d_in[7], (const float*)d_in[8],
      (const float*)d_in[9], (const float*)d_in[10],
      (const float*)d_in[11], (const float*)d_in[12]);
  lstm_wave_kernel<<<dim3(BB / 64), dim3(512), 0, stream>>>(
      (const float*)d_in[0], (const float*)d_in[1], (const float*)d_in[2],
      (float*)d_out);
}

// Round 10
// 1486.291 us; speedup vs baseline: 7.7918x; 2.2577x over previous
//
#include <hip/hip_runtime.h>
#include <math.h>

#define TT 200
#define BB 16384
#define HH 20

// f64 weight store (element offsets)
#define OWIH0 0        // 160   W_ih0 [80,2]
#define OWHH0 160      // 1600  W_hh0 [80,20]
#define OB0   1760     // 80    b_ih0 + b_hh0
#define OWIH1 1840     // 1600  W_ih1 [80,20]
#define OWHH1 3440     // 1600  W_hh1 [80,20]
#define OB1   5040     // 80    b_ih1 + b_hh1
#define OWDEC 5120     // 12000 W_dec [3,4000]
#define OBDEC 17120    // 3     b_dec
#define WTOT  17123

__device__ double g_wd[WTOT];

// ---------- JAX threefry2x32, key = jax.random.key(42) = [0, 42] ----------
__device__ __forceinline__ void tf2x32(unsigned x0, unsigned x1,
                                       unsigned* o0, unsigned* o1) {
  const unsigned ks0 = 0u, ks1 = 42u;
  const unsigned ks2 = ks0 ^ ks1 ^ 0x1BD11BDAu;
  x0 += ks0; x1 += ks1;
#define ROTL_(v, d) (((v) << (d)) | ((v) >> (32 - (d))))
#define RND_(r) { x0 += x1; x1 = ROTL_(x1, r); x1 ^= x0; }
  RND_(13) RND_(15) RND_(26) RND_(6)
  x0 += ks1; x1 += ks2 + 1u;
  RND_(17) RND_(29) RND_(16) RND_(24)
  x0 += ks2; x1 += ks0 + 2u;
  RND_(13) RND_(15) RND_(26) RND_(6)
  x0 += ks0; x1 += ks1 + 3u;
  RND_(17) RND_(29) RND_(16) RND_(24)
  x0 += ks1; x1 += ks2 + 4u;
  RND_(13) RND_(15) RND_(26) RND_(6)
  x0 += ks2; x1 += ks0 + 5u;
  *o0 = x0; *o1 = x1;
#undef RND_
#undef ROTL_
}

// uniform bits -> gumbel sample (f32 bit manipulation exact; logs in f64)
__device__ __forceinline__ double bits2gumbel(unsigned bits) {
  float f = __uint_as_float((bits >> 9) | 0x3F800000u) - 1.0f;
  float uf = (f > 0.0f) ? f : 1.17549435e-38f;  // max(tiny, f) semantics
  return -log(-log((double)uf));
}

// ---------- f32 activations (HW exp + rcp with 1 NR); ~1 ulp f32 ----------
__device__ __forceinline__ double sigm_f(double v) {
  float xf = (float)v;
  xf = fminf(fmaxf(xf, -30.0f), 30.0f);
  float e = __expf(-xf);
  float d = 1.0f + e;
  float r = __builtin_amdgcn_rcpf(d);
  r = r * (2.0f - d * r);
  return (double)r;
}
__device__ __forceinline__ double tanh_f(double v) {
  float xf = (float)v;
  xf = fminf(fmaxf(2.0f * xf, -60.0f), 60.0f);
  float e = __expf(xf);
  float d = 1.0f + e;
  float r = __builtin_amdgcn_rcpf(d);
  r = r * (2.0f - d * r);
  return (double)(1.0f - 2.0f * r);
}

__global__ void prep_kernel(
    const float* __restrict__ W_ih0, const float* __restrict__ W_hh0,
    const float* __restrict__ b_ih0, const float* __restrict__ b_hh0,
    const float* __restrict__ W_ih1, const float* __restrict__ W_hh1,
    const float* __restrict__ b_ih1, const float* __restrict__ b_hh1,
    const float* __restrict__ W_dec, const float* __restrict__ b_dec) {
  int i = blockIdx.x * blockDim.x + threadIdx.x;
  if (i < 160) g_wd[i] = (double)W_ih0[i];
  else if (i < 1760) g_wd[i] = (double)W_hh0[i - 160];
  else if (i < 1840) { int r = i - 1760; g_wd[i] = (double)b_ih0[r] + (double)b_hh0[r]; }
  else if (i < 3440) g_wd[i] = (double)W_ih1[i - 1840];
  else if (i < 5040) g_wd[i] = (double)W_hh1[i - 3440];
  else if (i < 5120) { int r = i - 5040; g_wd[i] = (double)b_ih1[r] + (double)b_hh1[r]; }
  else if (i < 17120) g_wd[i] = (double)W_dec[i - 5120];
  else if (i < WTOT) g_wd[i] = (double)b_dec[i - 17120];
}

// layer-0 chunk: NC units at rows row0..; f64 dots, f32 activations.
template <int NC>
__device__ __forceinline__ void l0_chunk(int row0, double x0, double x1,
                                         const double* hp, double* c_st,
                                         double* dst) {
  double acc[NC][4];
#pragma unroll
  for (int u = 0; u < NC; ++u) {
#pragma unroll
    for (int g = 0; g < 4; ++g) {
      int row = g * 20 + row0 + u;
      double a = g_wd[OB0 + row];
      a = fma(g_wd[OWIH0 + row * 2 + 0], x0, a);
      a = fma(g_wd[OWIH0 + row * 2 + 1], x1, a);
      acc[u][g] = a;
    }
  }
#pragma unroll
  for (int j = 0; j < HH; ++j) {
    double hj = hp[j];
#pragma unroll
    for (int u = 0; u < NC; ++u)
#pragma unroll
      for (int g = 0; g < 4; ++g)
        acc[u][g] = fma(g_wd[OWHH0 + (g * 20 + row0 + u) * HH + j], hj, acc[u][g]);
  }
#pragma unroll
  for (int u = 0; u < NC; ++u) {
    double si = sigm_f(acc[u][0]), sf = sigm_f(acc[u][1]);
    double tg = tanh_f(acc[u][2]), so = sigm_f(acc[u][3]);
    double c = fma(sf, c_st[u], si * tg);
    c_st[u] = c;
    dst[u] = so * tanh_f(c);
  }
}

// layer-1 chunk: NC units; hp0 cached in regs, recurrent h1 streamed from LDS.
template <int NC>
__device__ __forceinline__ void l1_chunk(int row0, const double* hp0,
                                         const double* h1r, double* c_st,
                                         double* dst, int t1, double* lg) {
  double acc[NC][4];
#pragma unroll
  for (int u = 0; u < NC; ++u)
#pragma unroll
    for (int g = 0; g < 4; ++g)
      acc[u][g] = g_wd[OB1 + g * 20 + row0 + u];
#pragma unroll
  for (int j = 0; j < HH; ++j) {
    double hj = hp0[j];
#pragma unroll
    for (int u = 0; u < NC; ++u)
#pragma unroll
      for (int g = 0; g < 4; ++g)
        acc[u][g] = fma(g_wd[OWIH1 + (g * 20 + row0 + u) * HH + j], hj, acc[u][g]);
  }
#pragma unroll
  for (int j = 0; j < HH; ++j) {
    double hj = h1r[j];  // LDS stream
#pragma unroll
    for (int u = 0; u < NC; ++u)
#pragma unroll
      for (int g = 0; g < 4; ++g)
        acc[u][g] = fma(g_wd[OWHH1 + (g * 20 + row0 + u) * HH + j], hj, acc[u][g]);
  }
#pragma unroll
  for (int u = 0; u < NC; ++u) {
    double si = sigm_f(acc[u][0]), sf = sigm_f(acc[u][1]);
    double tg = tanh_f(acc[u][2]), so = sigm_f(acc[u][3]);
    double c = fma(sf, c_st[u], si * tg);
    c_st[u] = c;
    double h = so * tanh_f(c);
    dst[u] = h;
    int col = t1 * HH + row0 + u;
    lg[0] = fma(g_wd[OWDEC + col], h, lg[0]);
    lg[1] = fma(g_wd[OWDEC + 4000 + col], h, lg[1]);
    lg[2] = fma(g_wd[OWDEC + 8000 + col], h, lg[2]);
  }
}

// 16 waves / 64 elements: waves 0-5 = layer-0 units {4,4,3,3,3,3};
// waves 6-15 = layer-1 units {2 each}, pipelined one step behind.
__global__ __launch_bounds__(1024, 4) void lstm_wave_kernel(
    const float* __restrict__ x,      // [T,B,2]
    const float* __restrict__ h0_in,  // [2,B,20]
    const float* __restrict__ c0_in,  // [2,B,20]
    float* __restrict__ out) {
  __shared__ double s_h0[2][64][21];   // stride 42 dwords, gcd(42,32)=2 -> free
  __shared__ double s_h1[2][64][21];
  __shared__ double s_logit[10][64][3];

  const int lane = threadIdx.x & 63;
  const int wv = __builtin_amdgcn_readfirstlane((int)(threadIdx.x >> 6));
  const int eg = blockIdx.x * 64 + lane;

  const bool isL0 = (wv < 6);
  int u0r, nur;
  if (isL0) {
    if (wv < 2) { u0r = wv * 4; nur = 4; }
    else        { u0r = 8 + (wv - 2) * 3; nur = 3; }
  } else {
    u0r = (wv - 6) * 2; nur = 2;
  }
  const int u0 = __builtin_amdgcn_readfirstlane(u0r);
  const int nu = __builtin_amdgcn_readfirstlane(nur);

  double c_st[4];
  double lg[3] = {0.0, 0.0, 0.0};

  // init: h(-1) into buffer 1 (phases 0/1 read it there)
  {
    const int l = isL0 ? 0 : 1;
#pragma unroll
    for (int u = 0; u < 4; ++u) {
      if (u < nu) {
        c_st[u] = (double)c0_in[l * BB * HH + eg * HH + u0 + u];
        double h = (double)h0_in[l * BB * HH + eg * HH + u0 + u];
        if (isL0) s_h0[1][lane][u0 + u] = h;
        else      s_h1[1][lane][u0 + u] = h;
      }
    }
  }
  __syncthreads();

  const float2* x2 = (const float2*)x;

  // phase s: L0 computes t=s (s<200): reads h0 buf (s+1)&1, writes s&1.
  //          L1 computes t1=s-1 (s>=1): h0(t1) from t1&1, own h1(t1-1) from
  //          (t1+1)&1, writes h1(t1) -> t1&1.
  for (int s = 0; s <= TT; ++s) {
    if (isL0) {
      if (s < TT) {
        const int rb = (s + 1) & 1;
        const int wb = s & 1;
        float2 xv = x2[s * BB + eg];
        double x0 = (double)xv.x, x1 = (double)xv.y;
        double hp[HH];
#pragma unroll
        for (int j = 0; j < HH; ++j) hp[j] = s_h0[rb][lane][j];
        double* dst = &s_h0[wb][lane][0];
        if (nu == 4) {
          l0_chunk<2>(u0 + 0, x0, x1, hp, c_st + 0, dst + u0 + 0);
          l0_chunk<2>(u0 + 2, x0, x1, hp, c_st + 2, dst + u0 + 2);
        } else {
          l0_chunk<2>(u0 + 0, x0, x1, hp, c_st + 0, dst + u0 + 0);
          l0_chunk<1>(u0 + 2, x0, x1, hp, c_st + 2, dst + u0 + 2);
        }
      }
    } else {
      if (s >= 1) {
        const int t1 = s - 1;
        const int h0b = t1 & 1;
        const int h1rb = (t1 + 1) & 1;
        double hp0[HH];
#pragma unroll
        for (int j = 0; j < HH; ++j) hp0[j] = s_h0[h0b][lane][j];
        const double* h1r = &s_h1[h1rb][lane][0];
        double* dst = &s_h1[h0b][lane][0];
        l1_chunk<2>(u0, hp0, h1r, c_st, dst + u0, t1, lg);
      }
    }
    __syncthreads();
  }

  // final states: h(199) in buffer 1 (199&1==1)
  {
    const int l = isL0 ? 0 : 1;
#pragma unroll
    for (int u = 0; u < 4; ++u) {
      if (u < nu) {
        double hfin = isL0 ? s_h0[1][lane][u0 + u] : s_h1[1][lane][u0 + u];
        out[2 * BB + l * BB * HH + eg * HH + u0 + u] = (float)hfin;
        out[2 * BB + 2 * BB * HH + l * BB * HH + eg * HH + u0 + u] = (float)c_st[u];
      }
    }
  }

  if (!isL0) {
    s_logit[wv - 6][lane][0] = lg[0];
    s_logit[wv - 6][lane][1] = lg[1];
    s_logit[wv - 6][lane][2] = lg[2];
  }
  __syncthreads();

  if (wv == 0) {
    double l[3];
#pragma unroll
    for (int a = 0; a < 3; ++a) {
      double v = g_wd[OBDEC + a];
#pragma unroll
      for (int k = 0; k < 10; ++k) v += s_logit[k][lane][a];
      l[a] = v;
    }

    // partitionable 32-bit stream: hi^lo of threefry2x32(key, (0, flat_idx))
    int act = 0;
    double vbest = -1.0e300;
#pragma unroll
    for (int a = 0; a < 3; ++a) {
      unsigned idx = 3u * (unsigned)eg + (unsigned)a;
      unsigned p0, p1;
      tf2x32(0u, idx, &p0, &p1);
      double g = bits2gumbel(p0 ^ p1);
      double v = l[a] + g;
      if (v > vbest) { vbest = v; act = a; }  // strict >: first max (argmax)
    }
    double m = fmax(l[0], fmax(l[1], l[2]));
    double se = exp(l[0] - m) + exp(l[1] - m) + exp(l[2] - m);
    double lp = (l[act] - m) - log(se);
    out[eg] = (float)act;
    out[BB + eg] = (float)lp;
  }
}

extern "C" void kernel_launch(void* const* d_in, const int* in_sizes, int n_in,
                              void* d_out, int out_size, void* d_ws, size_t ws_size,
                              hipStream_t stream) {
  prep_kernel<<<dim3((WTOT + 255) / 256), dim3(256), 0, stream>>>(
      (const float*)d_in[3], (const float*)d_in[4],
      (const float*)d_in[5], (const float*)d_in[6],
      (const float*)d_in[7], (const float*)d_in[8],
      (const float*)d_in[9], (const float*)d_in[10],
      (const float*)d_in[11], (const float*)d_in[12]);
  lstm_wave_kernel<<<dim3(BB / 64), dim3(1024), 0, stream>>>(
      (const float*)d_in[0], (const float*)d_in[1], (const float*)d_in[2],
      (float*)d_out);
}